// Round 7
// baseline (145.480 us; speedup 1.0000x reference)
//
#include <hip/hip_runtime.h>
#include <hip/hip_bf16.h>
#include <stdint.h>

// GPT2Attention: S=2048 E=1024 H=16 d=64 T=4096 past=2048, f32 in/out.
// Round 7: attn pipeline deepened (T3/T4): 3-buffer LDS, stage 2 tiles ahead,
// counted vmcnt(2) + raw s_barrier (no implicit drain), sched_barrier fence.
// Split-K rebalanced: chunk boundary at Kq/2 per q-block -> both chunks 17..32
// tiles (was 32 vs 2..32). Rest unchanged from round 6 (passed, 144us).

#define S_LEN 2048
#define E_DIM 1024
#define NHEAD 16
#define HDIM  64
#define T_LEN 4096
#define PASTL 2048

typedef __bf16 bf16x8 __attribute__((ext_vector_type(8)));
typedef float  f32x4  __attribute__((ext_vector_type(4)));

static __device__ __forceinline__ f32x4 mfma_bf16(bf16x8 a, bf16x8 b, f32x4 c) {
  return __builtin_amdgcn_mfma_f32_16x16x32_bf16(a, b, c, 0, 0, 0);
}

// RNE float -> bf16 bits (values are finite; no NaN path needed)
static __device__ __forceinline__ unsigned short f2bf(float f) {
  union { float f; unsigned int u; } v; v.f = f;
  unsigned int u = v.u;
  return (unsigned short)((u + 0x7fffu + ((u >> 16) & 1u)) >> 16);
}

#define GLOBAL_LOAD_LDS16(gptr, lptr)                                              \
  __builtin_amdgcn_global_load_lds(                                                \
      (const __attribute__((address_space(1))) unsigned int*)(gptr),               \
      (__attribute__((address_space(3))) unsigned int*)(lptr), 16, 0, 0)

// ---------------------------------------------------------------- aux kernels

__global__ void copy_past_kernel(const float* __restrict__ past,
                                 float* __restrict__ cache,
                                 unsigned short* __restrict__ kb) {
  const int n4 = (2 * NHEAD * T_LEN * HDIM) / 4;
  for (int i = blockIdx.x * blockDim.x + threadIdx.x; i < n4;
       i += gridDim.x * blockDim.x) {
    float4 v = ((const float4*)past)[i];
    ((float4*)cache)[i] = v;
    int e = i * 4;
    if (e < NHEAD * T_LEN * HDIM) {
      int t = (e >> 6) & (T_LEN - 1);
      if (t < PASTL) {
        ushort4 u;
        u.x = f2bf(v.x); u.y = f2bf(v.y); u.z = f2bf(v.z); u.w = f2bf(v.w);
        ((ushort4*)kb)[i] = u;
      }
    }
  }
}

__global__ void convert_kernel(const float* __restrict__ in,
                               unsigned short* __restrict__ out, int n4) {
  for (int i = blockIdx.x * blockDim.x + threadIdx.x; i < n4;
       i += gridDim.x * blockDim.x) {
    float4 v = ((const float4*)in)[i];
    ushort4 u;
    u.x = f2bf(v.x); u.y = f2bf(v.y); u.z = f2bf(v.z); u.w = f2bf(v.w);
    ((ushort4*)out)[i] = u;
  }
}

// in [rows][cols] f32 -> out [cols][rows] bf16
__global__ void transpose_convert_kernel(const float* __restrict__ in,
                                         unsigned short* __restrict__ out,
                                         int rows, int cols) {
  __shared__ float tile[64][65];
  const int c0 = blockIdx.x * 64, r0 = blockIdx.y * 64;
  const int tx = threadIdx.x & 63, ty = threadIdx.x >> 6;
#pragma unroll
  for (int r = 0; r < 64; r += 4)
    tile[r + ty][tx] = in[(size_t)(r0 + r + ty) * cols + c0 + tx];
  __syncthreads();
#pragma unroll
  for (int r = 0; r < 64; r += 4)
    out[(size_t)(c0 + r + ty) * rows + r0 + tx] = f2bf(tile[tx][r + ty]);
}

// cache_v f32 [H][T][64] -> vt bf16 [H][64][T]
__global__ void vtrans_kernel(const float* __restrict__ vin,
                              unsigned short* __restrict__ vt) {
  __shared__ float tile[64][65];
  const int h = blockIdx.y;
  const int t0 = blockIdx.x * 64;
  const float* in = vin + (size_t)h * T_LEN * HDIM;
  unsigned short* out = vt + (size_t)h * HDIM * T_LEN;
  const int tx = threadIdx.x & 63, ty = threadIdx.x >> 6;
#pragma unroll
  for (int r = 0; r < 64; r += 4)
    tile[r + ty][tx] = in[(size_t)(t0 + r + ty) * HDIM + tx];
  __syncthreads();
#pragma unroll
  for (int r = 0; r < 64; r += 4)
    out[(size_t)(r + ty) * T_LEN + t0 + tx] = f2bf(tile[tx][r + ty]);
}

// ---------------------------------------------------------------- GEMM (B^T)
// MODE 0: c_attn epilogue (q*0.125*log2e->bf16, k->cache+bf16, v->cache).
// MODE 1: f32 out.
template <int MODE>
__global__ __launch_bounds__(256) void gemm_bt_kernel(
    const unsigned short* __restrict__ A, const unsigned short* __restrict__ Bt,
    const float* __restrict__ bias, int K,
    float* __restrict__ out_f32, unsigned short* __restrict__ qb,
    float* __restrict__ cache_k, float* __restrict__ cache_v,
    unsigned short* __restrict__ kb) {
  __shared__ alignas(16) unsigned short As[128 * 64];
  __shared__ alignas(16) unsigned short Bs[128 * 64];
  const int tid = threadIdx.x;
  const int lane = tid & 63;
  const int w = tid >> 6;
  const int wm = w >> 1, wn = w & 1;
  const int m0 = blockIdx.y * 128, n0 = blockIdx.x * 128;

  f32x4 acc[4][4];
#pragma unroll
  for (int i = 0; i < 4; ++i)
#pragma unroll
    for (int j = 0; j < 4; ++j) acc[i][j] = f32x4{0.f, 0.f, 0.f, 0.f};

  const int rbase = w * 8 + (lane >> 3);
  const int sbase = lane & 7;

  for (int k0 = 0; k0 < K; k0 += 64) {
#pragma unroll
    for (int q = 0; q < 4; ++q) {
      int row_l = q * 32 + rbase;
      int slot = sbase ^ (row_l & 7);
      const unsigned short* ga = A + (size_t)(m0 + row_l) * K + k0 + slot * 8;
      const unsigned short* gb = Bt + (size_t)(n0 + row_l) * K + k0 + slot * 8;
      unsigned int ldsOff = (unsigned int)(q * 4096 + w * 1024);
      GLOBAL_LOAD_LDS16(ga, (char*)As + ldsOff);
      GLOBAL_LOAD_LDS16(gb, (char*)Bs + ldsOff);
    }
    __syncthreads();
#pragma unroll
    for (int kk = 0; kk < 2; ++kk) {
      bf16x8 af[4], bfr[4];
#pragma unroll
      for (int mi = 0; mi < 4; ++mi) {
        int row = wm * 64 + mi * 16 + (lane & 15);
        int slot = (kk * 4 + (lane >> 4)) ^ (row & 7);
        af[mi] = *reinterpret_cast<const bf16x8*>((const char*)As + row * 128 + slot * 16);
      }
#pragma unroll
      for (int ni = 0; ni < 4; ++ni) {
        int row = wn * 64 + ni * 16 + (lane & 15);
        int slot = (kk * 4 + (lane >> 4)) ^ (row & 7);
        bfr[ni] = *reinterpret_cast<const bf16x8*>((const char*)Bs + row * 128 + slot * 16);
      }
#pragma unroll
      for (int mi = 0; mi < 4; ++mi)
#pragma unroll
        for (int ni = 0; ni < 4; ++ni)
          acc[mi][ni] = mfma_bf16(af[mi], bfr[ni], acc[mi][ni]);
    }
    __syncthreads();
  }

#pragma unroll
  for (int ni = 0; ni < 4; ++ni) {
    int n = n0 + wn * 64 + ni * 16 + (lane & 15);
    float bv = bias[n];
#pragma unroll
    for (int mi = 0; mi < 4; ++mi) {
#pragma unroll
      for (int r = 0; r < 4; ++r) {
        int m = m0 + wm * 64 + mi * 16 + (lane >> 4) * 4 + r;
        float val = acc[mi][ni][r] + bv;
        if (MODE == 0) {
          if (n < E_DIM) {
            // fold 1/sqrt(d) * log2(e) for exp2-softmax
            qb[(size_t)m * E_DIM + n] = f2bf(val * 0.18033688f);
          } else if (n < 2 * E_DIM) {
            int e = n - E_DIM;
            size_t idx = ((size_t)(e >> 6) * T_LEN + (PASTL + m)) * HDIM + (e & 63);
            cache_k[idx] = val;
            kb[idx] = f2bf(val);
          } else {
            int e = n - 2 * E_DIM;
            size_t idx = ((size_t)(e >> 6) * T_LEN + (PASTL + m)) * HDIM + (e & 63);
            cache_v[idx] = val;
          }
        } else {
          out_f32[(size_t)m * E_DIM + n] = val;
        }
      }
    }
  }
}

// ---------------------------------------------------------------- attention
// 8 waves (512 thr)/block, 128 q-rows/block, KVBLK=64. 3-buffer LDS pipeline:
// stage issued 2 tiles ahead (after raw s_barrier), counted vmcnt(2) waits
// (vmcnt(0) only on last tile). Balanced split-K: chunk boundary Kq/2 per
// q-block -> both chunks Kq/128 tiles. No-max exp2 softmax, pure-sum merge.
// Race-safety: stage(i+2) is issued after barrier(i), which guarantees all
// waves finished compute(i-1) = previous occupant of buffer (i+2)%3.
__global__ __launch_bounds__(512) void attn_kernel(
    const unsigned short* __restrict__ qb, const unsigned short* __restrict__ kb,
    const unsigned short* __restrict__ vt,
    float* __restrict__ o_part, float* __restrict__ l_part) {
  __shared__ alignas(16) unsigned short Ks[3][64 * 64];
  __shared__ alignas(16) unsigned short Vs[3][64 * 64];
  __shared__ alignas(16) unsigned short p_lds[8][16][72];
  const int h = blockIdx.y;
  const int z = blockIdx.z;
  const int tid = threadIdx.x;
  const int w = tid >> 6;
  const int lane = tid & 63;
  const int lr = lane & 15;
  const int lg = lane >> 4;
  const int qb0 = blockIdx.x * 128;
  const int q0 = qb0 + w * 16;

  const unsigned short* qrow = qb + (size_t)(q0 + lr) * E_DIM + h * HDIM + lg * 8;
  const bf16x8 qf0 = *reinterpret_cast<const bf16x8*>(qrow);
  const bf16x8 qf1 = *reinterpret_cast<const bf16x8*>(qrow + 32);

  const unsigned short* kh = kb + (size_t)h * T_LEN * HDIM;
  const unsigned short* vh = vt + (size_t)h * HDIM * T_LEN;

  // staging: thread -> (row 0..63, seg 0..7); LDS dest linear, source pre-swizzled.
  const int srow = w * 8 + (lane >> 3);
  const int sseg = (lane & 7) ^ (srow & 7);
  const unsigned short* ksrc = kh + (size_t)srow * HDIM + sseg * 8;  // + t0*HDIM
  const unsigned short* vsrc = vh + (size_t)srow * T_LEN + sseg * 8; // + t0

  f32x4 o[4];
  float lsum[4];
#pragma unroll
  for (int i = 0; i < 4; ++i) {
    o[i] = f32x4{0.f, 0.f, 0.f, 0.f};
    lsum[i] = 0.f;
  }

  const int jmax = q0 + PASTL;        // visibility: col <= row + PASTL
  const int Kq = qb0 + 128 + PASTL;   // total keys for this q-block (mult of 128)
  const int half = Kq >> 1;           // chunk boundary (mult of 64)
  const int tbeg = z ? half : 0;
  const int tend = z ? Kq : half;
  const int NT = (tend - tbeg) >> 6;  // 17..32, block-uniform

  auto stage = [&](int b, int t0) {
    GLOBAL_LOAD_LDS16(ksrc + (size_t)t0 * HDIM, (char*)Ks[b] + w * 1024);
    GLOBAL_LOAD_LDS16(vsrc + t0, (char*)Vs[b] + w * 1024);
  };

  stage(0, tbeg);
  stage(1, tbeg + 64);  // NT >= 17 always
  int cur = 0, s2 = 2;
  int t0 = tbeg;
  for (int i = 0; i < NT; ++i, t0 += 64) {
    if (i + 1 < NT) {
      asm volatile("s_waitcnt vmcnt(2)" ::: "memory");  // tile i done; i+1 in flight
    } else {
      asm volatile("s_waitcnt vmcnt(0)" ::: "memory");
    }
    __builtin_amdgcn_s_barrier();
    __builtin_amdgcn_sched_barrier(0);
    if (i + 2 < NT) stage(s2, t0 + 128);

    // ---- QK^T from LDS (swizzled reads) ----
    f32x4 sc[4];
#pragma unroll
    for (int j = 0; j < 4; ++j) sc[j] = f32x4{0.f, 0.f, 0.f, 0.f};
    __builtin_amdgcn_s_setprio(1);
#pragma unroll
    for (int j = 0; j < 4; ++j) {
      int row = j * 16 + lr;
      int s0 = lg ^ (row & 7), s1 = (4 + lg) ^ (row & 7);
      bf16x8 kf0 = *reinterpret_cast<const bf16x8*>((const char*)Ks[cur] + row * 128 + s0 * 16);
      bf16x8 kf1 = *reinterpret_cast<const bf16x8*>((const char*)Ks[cur] + row * 128 + s1 * 16);
      sc[j] = mfma_bf16(qf0, kf0, sc[j]);
      sc[j] = mfma_bf16(qf1, kf1, sc[j]);
    }
    __builtin_amdgcn_s_setprio(0);

    // ---- softmax (no-max; scores pre-scaled by log2e/8 -> exp2) ----
    const bool partial = (t0 + 63 > jmax);
#pragma unroll
    for (int j = 0; j < 4; ++j) {
#pragma unroll
      for (int r = 0; r < 4; ++r) {
        float p = __builtin_amdgcn_exp2f(sc[j][r]);
        if (partial) {
          int col = t0 + j * 16 + lr;
          int row = q0 + lg * 4 + r;
          if (col > row + PASTL) p = 0.f;
        }
        lsum[r] += p;
        p_lds[w][lg * 4 + r][j * 16 + lr] = f2bf(p);
      }
    }

    bf16x8 pa0 = *reinterpret_cast<const bf16x8*>(&p_lds[w][lr][lg * 8]);
    bf16x8 pa1 = *reinterpret_cast<const bf16x8*>(&p_lds[w][lr][32 + lg * 8]);

    // ---- PV from LDS V^T tile (swizzled reads) ----
    __builtin_amdgcn_s_setprio(1);
#pragma unroll
    for (int jd = 0; jd < 4; ++jd) {
      int row = jd * 16 + lr;
      int s0 = lg ^ (row & 7), s1 = (4 + lg) ^ (row & 7);
      bf16x8 vf0 = *reinterpret_cast<const bf16x8*>((const char*)Vs[cur] + row * 128 + s0 * 16);
      bf16x8 vf1 = *reinterpret_cast<const bf16x8*>((const char*)Vs[cur] + row * 128 + s1 * 16);
      o[jd] = mfma_bf16(pa0, vf0, o[jd]);
      o[jd] = mfma_bf16(pa1, vf1, o[jd]);
    }
    __builtin_amdgcn_s_setprio(0);

    cur = (cur == 2) ? 0 : cur + 1;
    s2 = (s2 == 2) ? 0 : s2 + 1;
  }

#pragma unroll
  for (int r = 0; r < 4; ++r) {
#pragma unroll
    for (int off = 1; off < 16; off <<= 1) lsum[r] += __shfl_xor(lsum[r], off);
  }

  float* op = o_part + (((size_t)z * NHEAD + h) * S_LEN) * HDIM;
  float* lp = l_part + ((size_t)z * NHEAD + h) * S_LEN;
#pragma unroll
  for (int jd = 0; jd < 4; ++jd) {
#pragma unroll
    for (int r = 0; r < 4; ++r) {
      int row = q0 + lg * 4 + r;
      op[(size_t)row * HDIM + jd * 16 + lr] = o[jd][r];
    }
  }
  if (lr == 0) {
#pragma unroll
    for (int r = 0; r < 4; ++r) lp[q0 + lg * 4 + r] = lsum[r];
  }
}

// Merge the two T-chunk partials and normalize -> ab bf16 [row][E].
__global__ __launch_bounds__(256) void attn_merge_kernel(
    const float* __restrict__ o_part, const float* __restrict__ l_part,
    unsigned short* __restrict__ ab) {
  const int flat = blockIdx.x * 256 + threadIdx.x;
  const int d4 = flat & 15;
  const int row = (flat >> 4) & (S_LEN - 1);
  const int h = flat >> 15;
  const size_t base = (((size_t)h * S_LEN) + row) * HDIM + d4 * 4;
  const size_t cstride = (size_t)NHEAD * S_LEN * HDIM;
  float4 o0 = *(const float4*)(o_part + base);
  float4 o1 = *(const float4*)(o_part + cstride + base);
  float l = l_part[(size_t)h * S_LEN + row] +
            l_part[(size_t)NHEAD * S_LEN + (size_t)h * S_LEN + row];
  float inv = 1.f / l;
  ushort4 u;
  u.x = f2bf((o0.x + o1.x) * inv);
  u.y = f2bf((o0.y + o1.y) * inv);
  u.z = f2bf((o0.z + o1.z) * inv);
  u.w = f2bf((o0.w + o1.w) * inv);
  *(ushort4*)(ab + (size_t)row * E_DIM + h * HDIM + d4 * 4) = u;
}

// ---------------------------------------------------------------- launch

extern "C" void kernel_launch(void* const* d_in, const int* in_sizes, int n_in,
                              void* d_out, int out_size, void* d_ws, size_t ws_size,
                              hipStream_t stream) {
  (void)in_sizes; (void)n_in; (void)out_size; (void)ws_size;
  const float* x    = (const float*)d_in[0];
  const float* past = (const float*)d_in[1];
  const float* W1   = (const float*)d_in[2];
  const float* b1   = (const float*)d_in[3];
  const float* W2   = (const float*)d_in[4];
  const float* b2   = (const float*)d_in[5];

  float* out = (float*)d_out;
  float* cache_k = out + (size_t)S_LEN * E_DIM;
  float* cache_v = cache_k + (size_t)NHEAD * T_LEN * HDIM;

  // Workspace (~42.3 MB), lifetime-disjoint overlaps:
  //   [0,4)    xb -> ab ;  [4,12) w1t -> vt ;  [12,14) w2t
  //   [14,18)  qb ;  [18,26) kb ;  [26,42) o_part ;  [42,42.3) l_part
  char* ws = (char*)d_ws;
  unsigned short* xb  = (unsigned short*)(ws);
  unsigned short* ab  = (unsigned short*)(ws);
  unsigned short* w1t = (unsigned short*)(ws + (size_t)(4u  << 20));
  unsigned short* vt  = (unsigned short*)(ws + (size_t)(4u  << 20));
  unsigned short* w2t = (unsigned short*)(ws + (size_t)(12u << 20));
  unsigned short* qb  = (unsigned short*)(ws + (size_t)(14u << 20));
  unsigned short* kb  = (unsigned short*)(ws + (size_t)(18u << 20));
  float* o_part = (float*)(ws + (size_t)(26u << 20));
  float* l_part = (float*)(ws + (size_t)(42u << 20));

  copy_past_kernel<<<2048, 256, 0, stream>>>(past, cache_k, kb);
  convert_kernel<<<1024, 256, 0, stream>>>(x, xb, (S_LEN * E_DIM) / 4);
  transpose_convert_kernel<<<dim3(3072 / 64, 1024 / 64), 256, 0, stream>>>(W1, w1t, 1024, 3072);
  transpose_convert_kernel<<<dim3(1024 / 64, 1024 / 64), 256, 0, stream>>>(W2, w2t, 1024, 1024);
  gemm_bt_kernel<0><<<dim3(3072 / 128, 2048 / 128), 256, 0, stream>>>(
      xb, w1t, b1, 1024, nullptr, qb, cache_k, cache_v, kb);
  vtrans_kernel<<<dim3(T_LEN / 64, NHEAD), 256, 0, stream>>>(cache_v, vt);
  attn_kernel<<<dim3(S_LEN / 128, NHEAD, 2), 512, 0, stream>>>(qb, kb, vt, o_part, l_part);
  attn_merge_kernel<<<(NHEAD * S_LEN * 16) / 256, 256, 0, stream>>>(o_part, l_part, ab);
  gemm_bt_kernel<1><<<dim3(1024 / 128, 2048 / 128), 256, 0, stream>>>(
      ab, w2t, b2, 1024, out, nullptr, nullptr, nullptr, nullptr);
}

// Round 8
// 144.624 us; speedup vs baseline: 1.0059x; 1.0059x over previous
//
#include <hip/hip_runtime.h>
#include <hip/hip_bf16.h>
#include <stdint.h>

// GPT2Attention: S=2048 E=1024 H=16 d=64 T=4096 past=2048, f32 in/out.
// Round 8: attn is LDS-issue-bound (r7 post-mortem). Changes:
//  - 32 q-rows/wave (4 waves x 32 = 128 q/block): K/V LDS fragment reads
//    amortized over 2x work (DS per block-tile ~2480 -> ~1160 cy).
//  - swapped QK^T (mfma(K,Q), same fragments): P-values land 4-consecutive-keys
//    per lane -> bf16x4 pack + ds_write_b64 (4x fewer, wider P writes);
//    lsum becomes per-lane scalar (one cross-lane reduce at kernel end).
//  - round-6 2-buffer stage schedule (depth-2 proved null).

#define S_LEN 2048
#define E_DIM 1024
#define NHEAD 16
#define HDIM  64
#define T_LEN 4096
#define PASTL 2048

typedef __bf16 bf16x8 __attribute__((ext_vector_type(8)));
typedef __bf16 bf16x4 __attribute__((ext_vector_type(4)));
typedef float  f32x4  __attribute__((ext_vector_type(4)));

static __device__ __forceinline__ f32x4 mfma_bf16(bf16x8 a, bf16x8 b, f32x4 c) {
  return __builtin_amdgcn_mfma_f32_16x16x32_bf16(a, b, c, 0, 0, 0);
}

// RNE float -> bf16 bits (values are finite; no NaN path needed)
static __device__ __forceinline__ unsigned short f2bf(float f) {
  union { float f; unsigned int u; } v; v.f = f;
  unsigned int u = v.u;
  return (unsigned short)((u + 0x7fffu + ((u >> 16) & 1u)) >> 16);
}

#define GLOBAL_LOAD_LDS16(gptr, lptr)                                              \
  __builtin_amdgcn_global_load_lds(                                                \
      (const __attribute__((address_space(1))) unsigned int*)(gptr),               \
      (__attribute__((address_space(3))) unsigned int*)(lptr), 16, 0, 0)

// ---------------------------------------------------------------- aux kernels

__global__ void copy_past_kernel(const float* __restrict__ past,
                                 float* __restrict__ cache,
                                 unsigned short* __restrict__ kb) {
  const int n4 = (2 * NHEAD * T_LEN * HDIM) / 4;
  for (int i = blockIdx.x * blockDim.x + threadIdx.x; i < n4;
       i += gridDim.x * blockDim.x) {
    float4 v = ((const float4*)past)[i];
    ((float4*)cache)[i] = v;
    int e = i * 4;
    if (e < NHEAD * T_LEN * HDIM) {
      int t = (e >> 6) & (T_LEN - 1);
      if (t < PASTL) {
        ushort4 u;
        u.x = f2bf(v.x); u.y = f2bf(v.y); u.z = f2bf(v.z); u.w = f2bf(v.w);
        ((ushort4*)kb)[i] = u;
      }
    }
  }
}

__global__ void convert_kernel(const float* __restrict__ in,
                               unsigned short* __restrict__ out, int n4) {
  for (int i = blockIdx.x * blockDim.x + threadIdx.x; i < n4;
       i += gridDim.x * blockDim.x) {
    float4 v = ((const float4*)in)[i];
    ushort4 u;
    u.x = f2bf(v.x); u.y = f2bf(v.y); u.z = f2bf(v.z); u.w = f2bf(v.w);
    ((ushort4*)out)[i] = u;
  }
}

// in [rows][cols] f32 -> out [cols][rows] bf16
__global__ void transpose_convert_kernel(const float* __restrict__ in,
                                         unsigned short* __restrict__ out,
                                         int rows, int cols) {
  __shared__ float tile[64][65];
  const int c0 = blockIdx.x * 64, r0 = blockIdx.y * 64;
  const int tx = threadIdx.x & 63, ty = threadIdx.x >> 6;
#pragma unroll
  for (int r = 0; r < 64; r += 4)
    tile[r + ty][tx] = in[(size_t)(r0 + r + ty) * cols + c0 + tx];
  __syncthreads();
#pragma unroll
  for (int r = 0; r < 64; r += 4)
    out[(size_t)(c0 + r + ty) * rows + r0 + tx] = f2bf(tile[tx][r + ty]);
}

// cache_v f32 [H][T][64] -> vt bf16 [H][64][T]
__global__ void vtrans_kernel(const float* __restrict__ vin,
                              unsigned short* __restrict__ vt) {
  __shared__ float tile[64][65];
  const int h = blockIdx.y;
  const int t0 = blockIdx.x * 64;
  const float* in = vin + (size_t)h * T_LEN * HDIM;
  unsigned short* out = vt + (size_t)h * HDIM * T_LEN;
  const int tx = threadIdx.x & 63, ty = threadIdx.x >> 6;
#pragma unroll
  for (int r = 0; r < 64; r += 4)
    tile[r + ty][tx] = in[(size_t)(t0 + r + ty) * HDIM + tx];
  __syncthreads();
#pragma unroll
  for (int r = 0; r < 64; r += 4)
    out[(size_t)(r + ty) * T_LEN + t0 + tx] = f2bf(tile[tx][r + ty]);
}

// ---------------------------------------------------------------- GEMM (B^T)
// MODE 0: c_attn epilogue (q*0.125*log2e->bf16, k->cache+bf16, v->cache).
// MODE 1: f32 out.
template <int MODE>
__global__ __launch_bounds__(256) void gemm_bt_kernel(
    const unsigned short* __restrict__ A, const unsigned short* __restrict__ Bt,
    const float* __restrict__ bias, int K,
    float* __restrict__ out_f32, unsigned short* __restrict__ qb,
    float* __restrict__ cache_k, float* __restrict__ cache_v,
    unsigned short* __restrict__ kb) {
  __shared__ alignas(16) unsigned short As[128 * 64];
  __shared__ alignas(16) unsigned short Bs[128 * 64];
  const int tid = threadIdx.x;
  const int lane = tid & 63;
  const int w = tid >> 6;
  const int wm = w >> 1, wn = w & 1;
  const int m0 = blockIdx.y * 128, n0 = blockIdx.x * 128;

  f32x4 acc[4][4];
#pragma unroll
  for (int i = 0; i < 4; ++i)
#pragma unroll
    for (int j = 0; j < 4; ++j) acc[i][j] = f32x4{0.f, 0.f, 0.f, 0.f};

  const int rbase = w * 8 + (lane >> 3);
  const int sbase = lane & 7;

  for (int k0 = 0; k0 < K; k0 += 64) {
#pragma unroll
    for (int q = 0; q < 4; ++q) {
      int row_l = q * 32 + rbase;
      int slot = sbase ^ (row_l & 7);
      const unsigned short* ga = A + (size_t)(m0 + row_l) * K + k0 + slot * 8;
      const unsigned short* gb = Bt + (size_t)(n0 + row_l) * K + k0 + slot * 8;
      unsigned int ldsOff = (unsigned int)(q * 4096 + w * 1024);
      GLOBAL_LOAD_LDS16(ga, (char*)As + ldsOff);
      GLOBAL_LOAD_LDS16(gb, (char*)Bs + ldsOff);
    }
    __syncthreads();
#pragma unroll
    for (int kk = 0; kk < 2; ++kk) {
      bf16x8 af[4], bfr[4];
#pragma unroll
      for (int mi = 0; mi < 4; ++mi) {
        int row = wm * 64 + mi * 16 + (lane & 15);
        int slot = (kk * 4 + (lane >> 4)) ^ (row & 7);
        af[mi] = *reinterpret_cast<const bf16x8*>((const char*)As + row * 128 + slot * 16);
      }
#pragma unroll
      for (int ni = 0; ni < 4; ++ni) {
        int row = wn * 64 + ni * 16 + (lane & 15);
        int slot = (kk * 4 + (lane >> 4)) ^ (row & 7);
        bfr[ni] = *reinterpret_cast<const bf16x8*>((const char*)Bs + row * 128 + slot * 16);
      }
#pragma unroll
      for (int mi = 0; mi < 4; ++mi)
#pragma unroll
        for (int ni = 0; ni < 4; ++ni)
          acc[mi][ni] = mfma_bf16(af[mi], bfr[ni], acc[mi][ni]);
    }
    __syncthreads();
  }

#pragma unroll
  for (int ni = 0; ni < 4; ++ni) {
    int n = n0 + wn * 64 + ni * 16 + (lane & 15);
    float bv = bias[n];
#pragma unroll
    for (int mi = 0; mi < 4; ++mi) {
#pragma unroll
      for (int r = 0; r < 4; ++r) {
        int m = m0 + wm * 64 + mi * 16 + (lane >> 4) * 4 + r;
        float val = acc[mi][ni][r] + bv;
        if (MODE == 0) {
          if (n < E_DIM) {
            // fold 1/sqrt(d) * log2(e) for exp2-softmax
            qb[(size_t)m * E_DIM + n] = f2bf(val * 0.18033688f);
          } else if (n < 2 * E_DIM) {
            int e = n - E_DIM;
            size_t idx = ((size_t)(e >> 6) * T_LEN + (PASTL + m)) * HDIM + (e & 63);
            cache_k[idx] = val;
            kb[idx] = f2bf(val);
          } else {
            int e = n - 2 * E_DIM;
            size_t idx = ((size_t)(e >> 6) * T_LEN + (PASTL + m)) * HDIM + (e & 63);
            cache_v[idx] = val;
          }
        } else {
          out_f32[(size_t)m * E_DIM + n] = val;
        }
      }
    }
  }
}

// ---------------------------------------------------------------- attention
// 4 waves (256 thr)/block, 32 q-rows/wave (two 16-row sub-blocks), KVBLK=64.
// Swapped QK^T: sc = mfma(K,Q) -> D[key][q]: each lane holds 4 consecutive
// keys of ONE q-row per (sb,j) -> bf16x4 pack + ds_write_b64; pa reads feed PV
// directly (A-frag row = q = lane&15). K/V frags reused across both sb.
// No-max exp2 softmax; split-K halves; pure-sum merge.
__global__ __launch_bounds__(256) void attn_kernel(
    const unsigned short* __restrict__ qb, const unsigned short* __restrict__ kb,
    const unsigned short* __restrict__ vt,
    float* __restrict__ o_part, float* __restrict__ l_part) {
  __shared__ alignas(16) unsigned short Ks[2][64 * 64];
  __shared__ alignas(16) unsigned short Vs[2][64 * 64];
  __shared__ alignas(16) __bf16 p_lds[4][32][72];
  const int h = blockIdx.y;
  const int z = blockIdx.z;
  const int tid = threadIdx.x;
  const int w = tid >> 6;
  const int lane = tid & 63;
  const int lr = lane & 15;
  const int lg = lane >> 4;
  const int qb0 = blockIdx.x * 128;
  const int q0 = qb0 + w * 32;

  // Q fragments for the two 16-row sub-blocks (B-operand of swapped QK).
  const unsigned short* qr0 = qb + (size_t)(q0 + lr) * E_DIM + h * HDIM + lg * 8;
  const unsigned short* qr1 = qb + (size_t)(q0 + 16 + lr) * E_DIM + h * HDIM + lg * 8;
  const bf16x8 qf00 = *reinterpret_cast<const bf16x8*>(qr0);
  const bf16x8 qf01 = *reinterpret_cast<const bf16x8*>(qr0 + 32);
  const bf16x8 qf10 = *reinterpret_cast<const bf16x8*>(qr1);
  const bf16x8 qf11 = *reinterpret_cast<const bf16x8*>(qr1 + 32);

  const unsigned short* kh = kb + (size_t)h * T_LEN * HDIM;
  const unsigned short* vh = vt + (size_t)h * HDIM * T_LEN;

  // staging: 256 threads cover 32 rows x 8 segs per load round; rows 0..31 and
  // 32..63 via two rounds. Linear LDS dest (tid*16), source seg pre-swizzled
  // (row&7 invariant under +32).
  const int srow = tid >> 3;                    // 0..31
  const int sseg = (tid & 7) ^ (srow & 7);
  const unsigned short* ksrc = kh + (size_t)srow * HDIM + sseg * 8;
  const unsigned short* vsrc = vh + (size_t)srow * T_LEN + sseg * 8;

  f32x4 o[2][4];
  float lsum[2][2];
#pragma unroll
  for (int sb = 0; sb < 2; ++sb) {
    lsum[sb][0] = lsum[sb][1] = 0.f;
#pragma unroll
    for (int jd = 0; jd < 4; ++jd) o[sb][jd] = f32x4{0.f, 0.f, 0.f, 0.f};
  }

  const int jmaxq = q0 + PASTL;       // partial if t0+63 > jmaxq
  const int Kq = qb0 + 128 + PASTL;   // total keys for this q-block
  const int half = Kq >> 1;
  const int tbeg = z ? half : 0;
  const int tend = z ? Kq : half;

  auto stage = [&](int b, int t0) {
    GLOBAL_LOAD_LDS16(ksrc + (size_t)t0 * HDIM, (char*)Ks[b] + tid * 16);
    GLOBAL_LOAD_LDS16(ksrc + (size_t)(t0 + 32) * HDIM, (char*)Ks[b] + 4096 + tid * 16);
    GLOBAL_LOAD_LDS16(vsrc + t0, (char*)Vs[b] + tid * 16);
    GLOBAL_LOAD_LDS16(vsrc + t0 + (size_t)32 * T_LEN, (char*)Vs[b] + 4096 + tid * 16);
  };

  stage(0, tbeg);
  int cur = 0;
  for (int t0 = tbeg; t0 < tend; t0 += 64) {
    asm volatile("s_waitcnt vmcnt(0)" ::: "memory");
    __syncthreads();
    if (t0 + 64 < tend) stage(cur ^ 1, t0 + 64);

    // ---- K fragments (8 b128), shared by both sub-blocks ----
    bf16x8 kf[4][2];
#pragma unroll
    for (int j = 0; j < 4; ++j) {
      int row = j * 16 + lr;
      int s0 = lg ^ (row & 7), s1 = (4 + lg) ^ (row & 7);
      kf[j][0] = *reinterpret_cast<const bf16x8*>((const char*)Ks[cur] + row * 128 + s0 * 16);
      kf[j][1] = *reinterpret_cast<const bf16x8*>((const char*)Ks[cur] + row * 128 + s1 * 16);
    }

    // ---- swapped QK^T: D[key][q] ----
    f32x4 sc[2][4];
#pragma unroll
    for (int sb = 0; sb < 2; ++sb)
#pragma unroll
      for (int j = 0; j < 4; ++j) sc[sb][j] = f32x4{0.f, 0.f, 0.f, 0.f};
    __builtin_amdgcn_s_setprio(1);
#pragma unroll
    for (int j = 0; j < 4; ++j) {
      sc[0][j] = mfma_bf16(kf[j][0], qf00, sc[0][j]);
      sc[0][j] = mfma_bf16(kf[j][1], qf01, sc[0][j]);
      sc[1][j] = mfma_bf16(kf[j][0], qf10, sc[1][j]);
      sc[1][j] = mfma_bf16(kf[j][1], qf11, sc[1][j]);
    }
    __builtin_amdgcn_s_setprio(0);

    // ---- softmax: p = exp2(sc); lane holds keys j*16+lg*4+r of q-row lr ----
    const bool partial = (t0 + 63 > jmaxq);
    const int thr = q0 + PASTL - t0 + lr;  // key_idx > thr + sb*16 => masked
    const int lg4 = lg * 4;
#pragma unroll
    for (int sb = 0; sb < 2; ++sb) {
#pragma unroll
      for (int j = 0; j < 4; ++j) {
        bf16x4 pk;
#pragma unroll
        for (int r = 0; r < 4; ++r) {
          float p = __builtin_amdgcn_exp2f(sc[sb][j][r]);
          if (partial && (j * 16 + lg4 + r > thr + sb * 16)) p = 0.f;
          lsum[sb][r >> 1] += p;
          pk[r] = (__bf16)p;
        }
        *reinterpret_cast<bf16x4*>(&p_lds[w][sb * 16 + lr][j * 16 + lg4]) = pk;
      }
    }

    // ---- PV: A = P (row=q=lane&15), B = V^T frags (shared across sb) ----
    bf16x8 pa[2][2];
#pragma unroll
    for (int sb = 0; sb < 2; ++sb) {
      pa[sb][0] = *reinterpret_cast<const bf16x8*>(&p_lds[w][sb * 16 + lr][lg * 8]);
      pa[sb][1] = *reinterpret_cast<const bf16x8*>(&p_lds[w][sb * 16 + lr][32 + lg * 8]);
    }
    __builtin_amdgcn_s_setprio(1);
#pragma unroll
    for (int jd = 0; jd < 4; ++jd) {
      int row = jd * 16 + lr;
      int s0 = lg ^ (row & 7), s1 = (4 + lg) ^ (row & 7);
      bf16x8 vf0 = *reinterpret_cast<const bf16x8*>((const char*)Vs[cur] + row * 128 + s0 * 16);
      bf16x8 vf1 = *reinterpret_cast<const bf16x8*>((const char*)Vs[cur] + row * 128 + s1 * 16);
      o[0][jd] = mfma_bf16(pa[0][0], vf0, o[0][jd]);
      o[0][jd] = mfma_bf16(pa[0][1], vf1, o[0][jd]);
      o[1][jd] = mfma_bf16(pa[1][0], vf0, o[1][jd]);
      o[1][jd] = mfma_bf16(pa[1][1], vf1, o[1][jd]);
    }
    __builtin_amdgcn_s_setprio(0);
    cur ^= 1;
  }

  float* op = o_part + (((size_t)z * NHEAD + h) * S_LEN) * HDIM;
  float* lp = l_part + ((size_t)z * NHEAD + h) * S_LEN;
#pragma unroll
  for (int sb = 0; sb < 2; ++sb) {
    float ls = lsum[sb][0] + lsum[sb][1];
    ls += __shfl_xor(ls, 16);
    ls += __shfl_xor(ls, 32);
    if (lg == 0) lp[q0 + sb * 16 + lr] = ls;
#pragma unroll
    for (int jd = 0; jd < 4; ++jd) {
#pragma unroll
      for (int r = 0; r < 4; ++r) {
        int row = q0 + sb * 16 + lg * 4 + r;
        op[(size_t)row * HDIM + jd * 16 + lr] = o[sb][jd][r];
      }
    }
  }
}

// Merge the two T-chunk partials and normalize -> ab bf16 [row][E].
__global__ __launch_bounds__(256) void attn_merge_kernel(
    const float* __restrict__ o_part, const float* __restrict__ l_part,
    unsigned short* __restrict__ ab) {
  const int flat = blockIdx.x * 256 + threadIdx.x;
  const int d4 = flat & 15;
  const int row = (flat >> 4) & (S_LEN - 1);
  const int h = flat >> 15;
  const size_t base = (((size_t)h * S_LEN) + row) * HDIM + d4 * 4;
  const size_t cstride = (size_t)NHEAD * S_LEN * HDIM;
  float4 o0 = *(const float4*)(o_part + base);
  float4 o1 = *(const float4*)(o_part + cstride + base);
  float l = l_part[(size_t)h * S_LEN + row] +
            l_part[(size_t)NHEAD * S_LEN + (size_t)h * S_LEN + row];
  float inv = 1.f / l;
  ushort4 u;
  u.x = f2bf((o0.x + o1.x) * inv);
  u.y = f2bf((o0.y + o1.y) * inv);
  u.z = f2bf((o0.z + o1.z) * inv);
  u.w = f2bf((o0.w + o1.w) * inv);
  *(ushort4*)(ab + (size_t)row * E_DIM + h * HDIM + d4 * 4) = u;
}

// ---------------------------------------------------------------- launch

extern "C" void kernel_launch(void* const* d_in, const int* in_sizes, int n_in,
                              void* d_out, int out_size, void* d_ws, size_t ws_size,
                              hipStream_t stream) {
  (void)in_sizes; (void)n_in; (void)out_size; (void)ws_size;
  const float* x    = (const float*)d_in[0];
  const float* past = (const float*)d_in[1];
  const float* W1   = (const float*)d_in[2];
  const float* b1   = (const float*)d_in[3];
  const float* W2   = (const float*)d_in[4];
  const float* b2   = (const float*)d_in[5];

  float* out = (float*)d_out;
  float* cache_k = out + (size_t)S_LEN * E_DIM;
  float* cache_v = cache_k + (size_t)NHEAD * T_LEN * HDIM;

  // Workspace (~42.3 MB), lifetime-disjoint overlaps:
  //   [0,4)    xb -> ab ;  [4,12) w1t -> vt ;  [12,14) w2t
  //   [14,18)  qb ;  [18,26) kb ;  [26,42) o_part ;  [42,42.3) l_part
  char* ws = (char*)d_ws;
  unsigned short* xb  = (unsigned short*)(ws);
  unsigned short* ab  = (unsigned short*)(ws);
  unsigned short* w1t = (unsigned short*)(ws + (size_t)(4u  << 20));
  unsigned short* vt  = (unsigned short*)(ws + (size_t)(4u  << 20));
  unsigned short* w2t = (unsigned short*)(ws + (size_t)(12u << 20));
  unsigned short* qb  = (unsigned short*)(ws + (size_t)(14u << 20));
  unsigned short* kb  = (unsigned short*)(ws + (size_t)(18u << 20));
  float* o_part = (float*)(ws + (size_t)(26u << 20));
  float* l_part = (float*)(ws + (size_t)(42u << 20));

  copy_past_kernel<<<2048, 256, 0, stream>>>(past, cache_k, kb);
  convert_kernel<<<1024, 256, 0, stream>>>(x, xb, (S_LEN * E_DIM) / 4);
  transpose_convert_kernel<<<dim3(3072 / 64, 1024 / 64), 256, 0, stream>>>(W1, w1t, 1024, 3072);
  transpose_convert_kernel<<<dim3(1024 / 64, 1024 / 64), 256, 0, stream>>>(W2, w2t, 1024, 1024);
  gemm_bt_kernel<0><<<dim3(3072 / 128, 2048 / 128), 256, 0, stream>>>(
      xb, w1t, b1, 1024, nullptr, qb, cache_k, cache_v, kb);
  vtrans_kernel<<<dim3(T_LEN / 64, NHEAD), 256, 0, stream>>>(cache_v, vt);
  attn_kernel<<<dim3(S_LEN / 128, NHEAD, 2), 256, 0, stream>>>(qb, kb, vt, o_part, l_part);
  attn_merge_kernel<<<(NHEAD * S_LEN * 16) / 256, 256, 0, stream>>>(o_part, l_part, ab);
  gemm_bt_kernel<1><<<dim3(1024 / 128, 2048 / 128), 256, 0, stream>>>(
      ab, w2t, b2, 1024, out, nullptr, nullptr, nullptr, nullptr);
}

// Round 9
// 135.641 us; speedup vs baseline: 1.0725x; 1.0662x over previous
//
#include <hip/hip_runtime.h>
#include <hip/hip_bf16.h>
#include <stdint.h>

// GPT2Attention: S=2048 E=1024 H=16 d=64 T=4096 past=2048, f32 in/out.
// Round 9: grid-level attn fixes (r8 counters: FETCH 81MB = L2 thrash across
// 16 heads/XCD; Occupancy 14.7% = coarse-tail imbalance).
//  - balanced decomposition: <=16-tile key chunks, 896 blocks (56/head)
//  - XCD head-affinity: fid%8 == head%8 -> 2 heads (2MB K/V) per XCD L2
//  - o_part partials in bf16 (merge sums up to 4 chunks; l stays f32)
//  - copy_past only t<2048 (rows >=2048 overwritten by gemm epilogue)

#define S_LEN 2048
#define E_DIM 1024
#define NHEAD 16
#define HDIM  64
#define T_LEN 4096
#define PASTL 2048

typedef __bf16 bf16x8 __attribute__((ext_vector_type(8)));
typedef __bf16 bf16x4 __attribute__((ext_vector_type(4)));
typedef float  f32x4  __attribute__((ext_vector_type(4)));

static __device__ __forceinline__ f32x4 mfma_bf16(bf16x8 a, bf16x8 b, f32x4 c) {
  return __builtin_amdgcn_mfma_f32_16x16x32_bf16(a, b, c, 0, 0, 0);
}

// RNE float -> bf16 bits (values are finite; no NaN path needed)
static __device__ __forceinline__ unsigned short f2bf(float f) {
  union { float f; unsigned int u; } v; v.f = f;
  unsigned int u = v.u;
  return (unsigned short)((u + 0x7fffu + ((u >> 16) & 1u)) >> 16);
}

static __device__ __forceinline__ float bf2f(unsigned short u) {
  union { unsigned int u; float f; } v; v.u = (unsigned int)u << 16;
  return v.f;
}

#define GLOBAL_LOAD_LDS16(gptr, lptr)                                              \
  __builtin_amdgcn_global_load_lds(                                                \
      (const __attribute__((address_space(1))) unsigned int*)(gptr),               \
      (__attribute__((address_space(3))) unsigned int*)(lptr), 16, 0, 0)

// ---------------------------------------------------------------- aux kernels

// Copy past rows t<2048 -> cache (rows >=2048 are fully written by gemm<0>
// epilogue). For K half also emit bf16 kb.
__global__ void copy_past_kernel(const float* __restrict__ past,
                                 float* __restrict__ cache,
                                 unsigned short* __restrict__ kb) {
  const int n4 = (2 * NHEAD * PASTL * HDIM) / 4;  // compact: only t<2048
  for (int i = blockIdx.x * blockDim.x + threadIdx.x; i < n4;
       i += gridDim.x * blockDim.x) {
    int e = i * 4;
    int d = e & 63;
    int t = (e >> 6) & (PASTL - 1);
    int hh = (e >> 17) & (NHEAD - 1);
    int kv = e >> 21;
    size_t full = (((size_t)kv * NHEAD + hh) * T_LEN + t) * HDIM + d;
    float4 v = *(const float4*)(past + full);
    *(float4*)(cache + full) = v;
    if (kv == 0) {
      ushort4 u;
      u.x = f2bf(v.x); u.y = f2bf(v.y); u.z = f2bf(v.z); u.w = f2bf(v.w);
      *(ushort4*)(kb + full) = u;
    }
  }
}

__global__ void convert_kernel(const float* __restrict__ in,
                               unsigned short* __restrict__ out, int n4) {
  for (int i = blockIdx.x * blockDim.x + threadIdx.x; i < n4;
       i += gridDim.x * blockDim.x) {
    float4 v = ((const float4*)in)[i];
    ushort4 u;
    u.x = f2bf(v.x); u.y = f2bf(v.y); u.z = f2bf(v.z); u.w = f2bf(v.w);
    ((ushort4*)out)[i] = u;
  }
}

// in [rows][cols] f32 -> out [cols][rows] bf16
__global__ void transpose_convert_kernel(const float* __restrict__ in,
                                         unsigned short* __restrict__ out,
                                         int rows, int cols) {
  __shared__ float tile[64][65];
  const int c0 = blockIdx.x * 64, r0 = blockIdx.y * 64;
  const int tx = threadIdx.x & 63, ty = threadIdx.x >> 6;
#pragma unroll
  for (int r = 0; r < 64; r += 4)
    tile[r + ty][tx] = in[(size_t)(r0 + r + ty) * cols + c0 + tx];
  __syncthreads();
#pragma unroll
  for (int r = 0; r < 64; r += 4)
    out[(size_t)(c0 + r + ty) * rows + r0 + tx] = f2bf(tile[tx][r + ty]);
}

// cache_v f32 [H][T][64] -> vt bf16 [H][64][T]
__global__ void vtrans_kernel(const float* __restrict__ vin,
                              unsigned short* __restrict__ vt) {
  __shared__ float tile[64][65];
  const int h = blockIdx.y;
  const int t0 = blockIdx.x * 64;
  const float* in = vin + (size_t)h * T_LEN * HDIM;
  unsigned short* out = vt + (size_t)h * HDIM * T_LEN;
  const int tx = threadIdx.x & 63, ty = threadIdx.x >> 6;
#pragma unroll
  for (int r = 0; r < 64; r += 4)
    tile[r + ty][tx] = in[(size_t)(t0 + r + ty) * HDIM + tx];
  __syncthreads();
#pragma unroll
  for (int r = 0; r < 64; r += 4)
    out[(size_t)(r + ty) * T_LEN + t0 + tx] = f2bf(tile[tx][r + ty]);
}

// ---------------------------------------------------------------- GEMM (B^T)
// MODE 0: c_attn epilogue (q*0.125*log2e->bf16, k->cache+bf16, v->cache).
// MODE 1: f32 out.
template <int MODE>
__global__ __launch_bounds__(256) void gemm_bt_kernel(
    const unsigned short* __restrict__ A, const unsigned short* __restrict__ Bt,
    const float* __restrict__ bias, int K,
    float* __restrict__ out_f32, unsigned short* __restrict__ qb,
    float* __restrict__ cache_k, float* __restrict__ cache_v,
    unsigned short* __restrict__ kb) {
  __shared__ alignas(16) unsigned short As[128 * 64];
  __shared__ alignas(16) unsigned short Bs[128 * 64];
  const int tid = threadIdx.x;
  const int lane = tid & 63;
  const int w = tid >> 6;
  const int wm = w >> 1, wn = w & 1;
  const int m0 = blockIdx.y * 128, n0 = blockIdx.x * 128;

  f32x4 acc[4][4];
#pragma unroll
  for (int i = 0; i < 4; ++i)
#pragma unroll
    for (int j = 0; j < 4; ++j) acc[i][j] = f32x4{0.f, 0.f, 0.f, 0.f};

  const int rbase = w * 8 + (lane >> 3);
  const int sbase = lane & 7;

  for (int k0 = 0; k0 < K; k0 += 64) {
#pragma unroll
    for (int q = 0; q < 4; ++q) {
      int row_l = q * 32 + rbase;
      int slot = sbase ^ (row_l & 7);
      const unsigned short* ga = A + (size_t)(m0 + row_l) * K + k0 + slot * 8;
      const unsigned short* gb = Bt + (size_t)(n0 + row_l) * K + k0 + slot * 8;
      unsigned int ldsOff = (unsigned int)(q * 4096 + w * 1024);
      GLOBAL_LOAD_LDS16(ga, (char*)As + ldsOff);
      GLOBAL_LOAD_LDS16(gb, (char*)Bs + ldsOff);
    }
    __syncthreads();
#pragma unroll
    for (int kk = 0; kk < 2; ++kk) {
      bf16x8 af[4], bfr[4];
#pragma unroll
      for (int mi = 0; mi < 4; ++mi) {
        int row = wm * 64 + mi * 16 + (lane & 15);
        int slot = (kk * 4 + (lane >> 4)) ^ (row & 7);
        af[mi] = *reinterpret_cast<const bf16x8*>((const char*)As + row * 128 + slot * 16);
      }
#pragma unroll
      for (int ni = 0; ni < 4; ++ni) {
        int row = wn * 64 + ni * 16 + (lane & 15);
        int slot = (kk * 4 + (lane >> 4)) ^ (row & 7);
        bfr[ni] = *reinterpret_cast<const bf16x8*>((const char*)Bs + row * 128 + slot * 16);
      }
#pragma unroll
      for (int mi = 0; mi < 4; ++mi)
#pragma unroll
        for (int ni = 0; ni < 4; ++ni)
          acc[mi][ni] = mfma_bf16(af[mi], bfr[ni], acc[mi][ni]);
    }
    __syncthreads();
  }

#pragma unroll
  for (int ni = 0; ni < 4; ++ni) {
    int n = n0 + wn * 64 + ni * 16 + (lane & 15);
    float bv = bias[n];
#pragma unroll
    for (int mi = 0; mi < 4; ++mi) {
#pragma unroll
      for (int r = 0; r < 4; ++r) {
        int m = m0 + wm * 64 + mi * 16 + (lane >> 4) * 4 + r;
        float val = acc[mi][ni][r] + bv;
        if (MODE == 0) {
          if (n < E_DIM) {
            // fold 1/sqrt(d) * log2(e) for exp2-softmax
            qb[(size_t)m * E_DIM + n] = f2bf(val * 0.18033688f);
          } else if (n < 2 * E_DIM) {
            int e = n - E_DIM;
            size_t idx = ((size_t)(e >> 6) * T_LEN + (PASTL + m)) * HDIM + (e & 63);
            cache_k[idx] = val;
            kb[idx] = f2bf(val);
          } else {
            int e = n - 2 * E_DIM;
            size_t idx = ((size_t)(e >> 6) * T_LEN + (PASTL + m)) * HDIM + (e & 63);
            cache_v[idx] = val;
          }
        } else {
          out_f32[(size_t)m * E_DIM + n] = val;
        }
      }
    }
  }
}

// ---------------------------------------------------------------- attention
// 4 waves (256 thr)/block, 32 q-rows/wave, KVBLK=64, swapped QK^T (r8).
// Work decomposition: 56 chunks/head (q-block x in 0..15 has NTfull=34+2x
// key-tiles, chunked into <=16-tile pieces: 3 chunks for x<8, 4 for x>=8).
// fid%8 == head%8 -> per-XCD L2 holds only 2 heads' K/V (2MB).
// No-max exp2 softmax; per-chunk bf16 o partials + f32 l partials.
__global__ __launch_bounds__(256) void attn_kernel(
    const unsigned short* __restrict__ qb, const unsigned short* __restrict__ kb,
    const unsigned short* __restrict__ vt,
    unsigned short* __restrict__ o_part, float* __restrict__ l_part) {
  __shared__ alignas(16) unsigned short Ks[2][64 * 64];
  __shared__ alignas(16) unsigned short Vs[2][64 * 64];
  __shared__ alignas(16) __bf16 p_lds[4][32][72];
  const int fid = blockIdx.x;  // 0..895
  const int h = (fid & 7) + ((fid >= 448) ? 8 : 0);
  const int g = (fid >> 3) - ((fid >= 448) ? 56 : 0);  // 0..55
  int x, c;
  if (g < 24) { x = g / 3; c = g - 3 * x; }
  else { int g2 = g - 24; x = 8 + (g2 >> 2); c = g2 & 3; }

  const int tid = threadIdx.x;
  const int w = tid >> 6;
  const int lane = tid & 63;
  const int lr = lane & 15;
  const int lg = lane >> 4;
  const int qb0 = x * 128;
  const int q0 = qb0 + w * 32;

  const unsigned short* qr0 = qb + (size_t)(q0 + lr) * E_DIM + h * HDIM + lg * 8;
  const unsigned short* qr1 = qb + (size_t)(q0 + 16 + lr) * E_DIM + h * HDIM + lg * 8;
  const bf16x8 qf00 = *reinterpret_cast<const bf16x8*>(qr0);
  const bf16x8 qf01 = *reinterpret_cast<const bf16x8*>(qr0 + 32);
  const bf16x8 qf10 = *reinterpret_cast<const bf16x8*>(qr1);
  const bf16x8 qf11 = *reinterpret_cast<const bf16x8*>(qr1 + 32);

  const unsigned short* kh = kb + (size_t)h * T_LEN * HDIM;
  const unsigned short* vh = vt + (size_t)h * HDIM * T_LEN;

  const int srow = tid >> 3;  // 0..31
  const int sseg = (tid & 7) ^ (srow & 7);
  const unsigned short* ksrc = kh + (size_t)srow * HDIM + sseg * 8;
  const unsigned short* vsrc = vh + (size_t)srow * T_LEN + sseg * 8;

  f32x4 o[2][4];
  float lsum[2][2];
#pragma unroll
  for (int sb = 0; sb < 2; ++sb) {
    lsum[sb][0] = lsum[sb][1] = 0.f;
#pragma unroll
    for (int jd = 0; jd < 4; ++jd) o[sb][jd] = f32x4{0.f, 0.f, 0.f, 0.f};
  }

  const int jmaxq = q0 + PASTL;
  const int NTfull = 34 + 2 * x;                        // key-tiles for this x
  const int tb = c * 16;
  const int te = (tb + 16 < NTfull) ? tb + 16 : NTfull; // <=16 tiles
  const int tbeg = tb * 64, tend = te * 64;

  auto stage = [&](int b, int t0) {
    GLOBAL_LOAD_LDS16(ksrc + (size_t)t0 * HDIM, (char*)Ks[b] + tid * 16);
    GLOBAL_LOAD_LDS16(ksrc + (size_t)(t0 + 32) * HDIM, (char*)Ks[b] + 4096 + tid * 16);
    GLOBAL_LOAD_LDS16(vsrc + t0, (char*)Vs[b] + tid * 16);
    GLOBAL_LOAD_LDS16(vsrc + t0 + (size_t)32 * T_LEN, (char*)Vs[b] + 4096 + tid * 16);
  };

  stage(0, tbeg);
  int cur = 0;
  for (int t0 = tbeg; t0 < tend; t0 += 64) {
    asm volatile("s_waitcnt vmcnt(0)" ::: "memory");
    __syncthreads();
    if (t0 + 64 < tend) stage(cur ^ 1, t0 + 64);

    // ---- K fragments (shared by both 16-row sub-blocks) ----
    bf16x8 kf[4][2];
#pragma unroll
    for (int j = 0; j < 4; ++j) {
      int row = j * 16 + lr;
      int s0 = lg ^ (row & 7), s1 = (4 + lg) ^ (row & 7);
      kf[j][0] = *reinterpret_cast<const bf16x8*>((const char*)Ks[cur] + row * 128 + s0 * 16);
      kf[j][1] = *reinterpret_cast<const bf16x8*>((const char*)Ks[cur] + row * 128 + s1 * 16);
    }

    // ---- swapped QK^T: D[key][q] ----
    f32x4 sc[2][4];
#pragma unroll
    for (int sb = 0; sb < 2; ++sb)
#pragma unroll
      for (int j = 0; j < 4; ++j) sc[sb][j] = f32x4{0.f, 0.f, 0.f, 0.f};
    __builtin_amdgcn_s_setprio(1);
#pragma unroll
    for (int j = 0; j < 4; ++j) {
      sc[0][j] = mfma_bf16(kf[j][0], qf00, sc[0][j]);
      sc[0][j] = mfma_bf16(kf[j][1], qf01, sc[0][j]);
      sc[1][j] = mfma_bf16(kf[j][0], qf10, sc[1][j]);
      sc[1][j] = mfma_bf16(kf[j][1], qf11, sc[1][j]);
    }
    __builtin_amdgcn_s_setprio(0);

    // ---- softmax: p = exp2(sc); lane holds keys j*16+lg*4+r of q-row lr ----
    const bool partial = (t0 + 63 > jmaxq);
    const int thr = q0 + PASTL - t0 + lr;
    const int lg4 = lg * 4;
#pragma unroll
    for (int sb = 0; sb < 2; ++sb) {
#pragma unroll
      for (int j = 0; j < 4; ++j) {
        bf16x4 pk;
#pragma unroll
        for (int r = 0; r < 4; ++r) {
          float p = __builtin_amdgcn_exp2f(sc[sb][j][r]);
          if (partial && (j * 16 + lg4 + r > thr + sb * 16)) p = 0.f;
          lsum[sb][r >> 1] += p;
          pk[r] = (__bf16)p;
        }
        *reinterpret_cast<bf16x4*>(&p_lds[w][sb * 16 + lr][j * 16 + lg4]) = pk;
      }
    }

    // ---- PV ----
    bf16x8 pa[2][2];
#pragma unroll
    for (int sb = 0; sb < 2; ++sb) {
      pa[sb][0] = *reinterpret_cast<const bf16x8*>(&p_lds[w][sb * 16 + lr][lg * 8]);
      pa[sb][1] = *reinterpret_cast<const bf16x8*>(&p_lds[w][sb * 16 + lr][32 + lg * 8]);
    }
    __builtin_amdgcn_s_setprio(1);
#pragma unroll
    for (int jd = 0; jd < 4; ++jd) {
      int row = jd * 16 + lr;
      int s0 = lg ^ (row & 7), s1 = (4 + lg) ^ (row & 7);
      bf16x8 vf0 = *reinterpret_cast<const bf16x8*>((const char*)Vs[cur] + row * 128 + s0 * 16);
      bf16x8 vf1 = *reinterpret_cast<const bf16x8*>((const char*)Vs[cur] + row * 128 + s1 * 16);
      o[0][jd] = mfma_bf16(pa[0][0], vf0, o[0][jd]);
      o[0][jd] = mfma_bf16(pa[0][1], vf1, o[0][jd]);
      o[1][jd] = mfma_bf16(pa[1][0], vf0, o[1][jd]);
      o[1][jd] = mfma_bf16(pa[1][1], vf1, o[1][jd]);
    }
    __builtin_amdgcn_s_setprio(0);
    cur ^= 1;
  }

  // partials: o_part[c][h][row][d] bf16, l_part[c][h][row] f32
  unsigned short* op = o_part + ((size_t)(c * NHEAD + h) * S_LEN) * HDIM;
  float* lp = l_part + (size_t)(c * NHEAD + h) * S_LEN;
#pragma unroll
  for (int sb = 0; sb < 2; ++sb) {
    float ls = lsum[sb][0] + lsum[sb][1];
    ls += __shfl_xor(ls, 16);
    ls += __shfl_xor(ls, 32);
    if (lg == 0) lp[q0 + sb * 16 + lr] = ls;
#pragma unroll
    for (int jd = 0; jd < 4; ++jd) {
#pragma unroll
      for (int r = 0; r < 4; ++r) {
        int row = q0 + sb * 16 + lg * 4 + r;
        op[(size_t)row * HDIM + jd * 16 + lr] = f2bf(o[sb][jd][r]);
      }
    }
  }
}

// Merge chunk partials (3 for rows<1024, 4 otherwise) and normalize -> ab bf16.
__global__ __launch_bounds__(256) void attn_merge_kernel(
    const unsigned short* __restrict__ o_part, const float* __restrict__ l_part,
    unsigned short* __restrict__ ab) {
  const int flat = blockIdx.x * 256 + threadIdx.x;
  const int d4 = flat & 15;
  const int row = (flat >> 4) & (S_LEN - 1);
  const int h = flat >> 15;
  const int nc = (row < 1024) ? 3 : 4;
  const size_t cstride_o = (size_t)NHEAD * S_LEN * HDIM;
  const size_t base_o = (((size_t)h * S_LEN) + row) * HDIM + d4 * 4;
  float acc[4] = {0.f, 0.f, 0.f, 0.f};
  float l = 0.f;
  for (int cc = 0; cc < nc; ++cc) {
    ushort4 u = *(const ushort4*)(o_part + cc * cstride_o + base_o);
    acc[0] += bf2f(u.x); acc[1] += bf2f(u.y);
    acc[2] += bf2f(u.z); acc[3] += bf2f(u.w);
    l += l_part[(size_t)cc * NHEAD * S_LEN + (size_t)h * S_LEN + row];
  }
  float inv = 1.f / l;
  ushort4 u;
  u.x = f2bf(acc[0] * inv);
  u.y = f2bf(acc[1] * inv);
  u.z = f2bf(acc[2] * inv);
  u.w = f2bf(acc[3] * inv);
  *(ushort4*)(ab + (size_t)row * E_DIM + h * HDIM + d4 * 4) = u;
}

// ---------------------------------------------------------------- launch

extern "C" void kernel_launch(void* const* d_in, const int* in_sizes, int n_in,
                              void* d_out, int out_size, void* d_ws, size_t ws_size,
                              hipStream_t stream) {
  (void)in_sizes; (void)n_in; (void)out_size; (void)ws_size;
  const float* x    = (const float*)d_in[0];
  const float* past = (const float*)d_in[1];
  const float* W1   = (const float*)d_in[2];
  const float* b1   = (const float*)d_in[3];
  const float* W2   = (const float*)d_in[4];
  const float* b2   = (const float*)d_in[5];

  float* out = (float*)d_out;
  float* cache_k = out + (size_t)S_LEN * E_DIM;
  float* cache_v = cache_k + (size_t)NHEAD * T_LEN * HDIM;

  // Workspace (~42.5 MB), lifetime-disjoint overlaps:
  //   [0,4)   xb -> ab ; [4,12) w1t -> vt ; [12,14) w2t
  //   [14,18) qb ; [18,26) kb ; [26,42) o_part bf16 [4][16][2048][64]
  //   [42,42.5) l_part f32 [4][16][2048]
  char* ws = (char*)d_ws;
  unsigned short* xb  = (unsigned short*)(ws);
  unsigned short* ab  = (unsigned short*)(ws);
  unsigned short* w1t = (unsigned short*)(ws + (size_t)(4u  << 20));
  unsigned short* vt  = (unsigned short*)(ws + (size_t)(4u  << 20));
  unsigned short* w2t = (unsigned short*)(ws + (size_t)(12u << 20));
  unsigned short* qb  = (unsigned short*)(ws + (size_t)(14u << 20));
  unsigned short* kb  = (unsigned short*)(ws + (size_t)(18u << 20));
  unsigned short* o_part = (unsigned short*)(ws + (size_t)(26u << 20));
  float* l_part = (float*)(ws + (size_t)(42u << 20));

  copy_past_kernel<<<2048, 256, 0, stream>>>(past, cache_k, kb);
  convert_kernel<<<1024, 256, 0, stream>>>(x, xb, (S_LEN * E_DIM) / 4);
  transpose_convert_kernel<<<dim3(3072 / 64, 1024 / 64), 256, 0, stream>>>(W1, w1t, 1024, 3072);
  transpose_convert_kernel<<<dim3(1024 / 64, 1024 / 64), 256, 0, stream>>>(W2, w2t, 1024, 1024);
  gemm_bt_kernel<0><<<dim3(3072 / 128, 2048 / 128), 256, 0, stream>>>(
      xb, w1t, b1, 1024, nullptr, qb, cache_k, cache_v, kb);
  vtrans_kernel<<<dim3(T_LEN / 64, NHEAD), 256, 0, stream>>>(cache_v, vt);
  attn_kernel<<<dim3(896), 256, 0, stream>>>(qb, kb, vt, o_part, l_part);
  attn_merge_kernel<<<(NHEAD * S_LEN * 16) / 256, 256, 0, stream>>>(o_part, l_part, ab);
  gemm_bt_kernel<1><<<dim3(1024 / 128, 2048 / 128), 256, 0, stream>>>(
      ab, w2t, b2, 1024, out, nullptr, nullptr, nullptr, nullptr);
}